// Round 14
// baseline (25.668 us; speedup 1.0000x reference)
//
#include <hip/hip_runtime.h>
#include <hip/hip_bf16.h>

// Decompose: algebraically a single 5x5 conv with scalar taps
//   a_k = wS_k . wE_k  (k = i*5+j), bias = sum_k (wS_k . bE_k + bS_k)
//   out = clip( (sum_k a_k * xp[h+i, w+j] + bias) / 25, 0, 1 )
// over xp = reflect-pad(clip(x,0,1), 2). Shapes: x (4,3,1024,1024) fp32.
//
// R14 = R13 with TBH 16->8 (grid 1536 = 6 blocks/CU). Diagnosis: R9-R13
// all stall ~800cyc/row-iter; compiler pins VGPR=72 (no MLP), and the
// 768-block grid supplied only 3 waves/SIMD of TLP -> SIMD idle ~50%.
// VGPR 72 admits 7 waves/SIMD; give the grid that lets 6 run: 1536 blocks
// = 24 waves/CU. PF 8->6 keeps buffer regs at 48 so total stays <=85
// (6 waves/SIMD needs <=85 VGPR).

#define HH 1024
#define WW 1024
#define NIMG 12
#define TBH 8              // output rows per block
#define ROWS (TBH + 4)     // 12 input rows touched
#define PF 6               // rolling load-buffer depth (rows)

typedef float f32x4 __attribute__((ext_vector_type(4)));
typedef float f32x2 __attribute__((ext_vector_type(2)));

__device__ __forceinline__ float readlane_f(float v, int lane) {
    return __int_as_float(__builtin_amdgcn_readlane(__float_as_int(v), lane));
}

__device__ __forceinline__ float sgpr_bcast(float v) {
    return __int_as_float(__builtin_amdgcn_readfirstlane(__float_as_int(v)));
}

__device__ __forceinline__ float dot4(f32x4 a, f32x4 b) {
    return a.x * b.x + a.y * b.y + a.z * b.z + a.w * b.w;
}

__device__ __forceinline__ f32x4 clip01v4(f32x4 v) {
    f32x4 z = {0.f, 0.f, 0.f, 0.f};
    f32x4 o = {1.f, 1.f, 1.f, 1.f};
    return __builtin_elementwise_min(__builtin_elementwise_max(v, z), o);
}

__device__ __forceinline__ f32x2 clip01v2(f32x2 v) {
    f32x2 z = {0.f, 0.f};
    f32x2 o = {1.f, 1.f};
    return __builtin_elementwise_min(__builtin_elementwise_max(v, z), o);
}

__global__ __launch_bounds__(256) void conv5_kernel(const float* __restrict__ x,
                                                    const float* __restrict__ wE,
                                                    const float* __restrict__ bE,
                                                    const float* __restrict__ wS,
                                                    const float* __restrict__ bS,
                                                    float* __restrict__ out) {
    int lane = threadIdx.x & 63;

    // ---- Lane-parallel constant prep (per wave, redundant; ~300 cyc) ----
    float apass[2], cacc = 0.f;
    #pragma unroll
    for (int p = 0; p < 2; ++p) {
        int k = p * 16 + (lane >> 2);
        float a = 0.f;
        if (k < 25) {
            int base = k * 64 + (lane & 3) * 16;
            #pragma unroll
            for (int i = 0; i < 4; ++i) {
                f32x4 sv = *(const f32x4*)(wS + base + 4 * i);
                f32x4 ev = *(const f32x4*)(wE + base + 4 * i);
                f32x4 bv = *(const f32x4*)(bE + base + 4 * i);
                a += dot4(sv, ev);
                cacc += dot4(sv, bv);
            }
        }
        a += __shfl_xor(a, 1);
        a += __shfl_xor(a, 2);     // all 4 lanes of the group hold a_k
        apass[p] = a;
    }
    if (lane < 25) cacc += bS[lane];
    #pragma unroll
    for (int off = 32; off; off >>= 1) cacc += __shfl_xor(cacc, off);
    float bias = sgpr_bcast(cacc * (1.f / 25.f));
    f32x2 bias2 = {bias, bias};

    float wv[25];
    #pragma unroll
    for (int k = 0; k < 16; ++k) wv[k] = readlane_f(apass[0], 4 * k) * (1.f / 25.f);
    #pragma unroll
    for (int k = 16; k < 25; ++k) wv[k] = readlane_f(apass[1], 4 * (k - 16)) * (1.f / 25.f);

    // ---- Tile mapping: XCD-aware bijective swizzle (1536 % 8 == 0) ----
    int nwg = gridDim.x;
    int cpx = nwg >> 3;
    int l = (blockIdx.x & 7) * cpx + (blockIdx.x >> 3);
    int img = l >> 7;                         // 128 row-blocks per image
    int rb = l & 127;
    int row0 = rb * TBH;

    const float* src = x + (size_t)img * (HH * WW);
    int tid = threadIdx.x;
    int cbase = tid * 4;                      // output col base

    // Column window: source cols cbase-2 .. cbase+5 (reflect at edges).
    bool lt = (cbase == 0);
    bool rt = (cbase == 1020);
    int qa = lt ? 0 : cbase - 2;
    int qb = rt ? 1020 : cbase + 2;

    // Row pointer with vertical reflection (block-uniform scalar math).
    auto rowptr = [&](int ir) -> const float* {
        int prow = row0 - 2 + ir;
        int sr = prow < 0 ? -prow : (prow >= HH ? 2 * HH - 2 - prow : prow);
        return src + (size_t)sr * WW;
    };

    // ---- Rolling structures ----
    f32x4 bufA[PF], bufB[PF];        // load pipeline, depth 6 rows
    f32x2 acc[5][2];                 // rotating output-row accumulators (packed)

    #pragma unroll
    for (int ir = 0; ir < PF; ++ir) {
        const float* rp = rowptr(ir);
        bufA[ir] = *(const f32x4*)(rp + qa);
        bufB[ir] = *(const f32x4*)(rp + qb);
    }
    __builtin_amdgcn_sched_barrier(0);   // keep prologue loads hoisted

    float* op = out + (size_t)img * (HH * WW) + (size_t)row0 * WW + cbase;

    #pragma unroll
    for (int ir = 0; ir < ROWS; ++ir) {
        f32x4 A = bufA[ir % PF];
        f32x4 B = bufB[ir % PF];
        if (ir + PF < ROWS) {
            const float* rp = rowptr(ir + PF);
            bufA[ir % PF] = *(const f32x4*)(rp + qa);
            bufB[ir % PF] = *(const f32x4*)(rp + qb);
        }

        // Packed clip (window selection below permutes clipped values).
        A = clip01v4(A);
        B = clip01v4(B);

        // Branchless window extraction (loop-invariant lt/rt masks).
        float r8[8] = {A.x, A.y, A.z, A.w, B.x, B.y, B.z, B.w};
        r8[0] = lt ? A.z : r8[0];
        r8[2] = lt ? A.x : r8[2];
        r8[3] = lt ? A.y : r8[3];
        r8[4] = rt ? B.z : r8[4];
        r8[5] = rt ? B.w : r8[5];
        r8[7] = rt ? B.y : r8[7];

        // Sliding pairs: pr[j] = {r8[j], r8[j+1]}, j = 0..6.
        f32x2 pr[7];
        #pragma unroll
        for (int j = 0; j < 7; ++j) { pr[j].x = r8[j]; pr[j].y = r8[j + 1]; }

        // Output row ir starts here: init its slot with the bias.
        if (ir < TBH) {
            acc[ir % 5][0] = bias2;
            acc[ir % 5][1] = bias2;
        }

        // Input row ir contributes to output rows ir-4 .. ir (packed FMA).
        #pragma unroll
        for (int dr = 0; dr < 5; ++dr) {
            int orow = ir - dr;
            if (orow < 0 || orow >= TBH) continue;
            #pragma unroll
            for (int j = 0; j < 5; ++j) {
                float wj = wv[dr * 5 + j];
                f32x2 w2 = {wj, wj};
                acc[orow % 5][0] += pr[j] * w2;       // cols 0,1
                acc[orow % 5][1] += pr[j + 2] * w2;   // cols 2,3
            }
        }

        // Output row ir-4 is final: packed clip, plain coalesced store.
        if (ir >= 4) {
            int orow = ir - 4;
            f32x2 lo = clip01v2(acc[orow % 5][0]);
            f32x2 hi = clip01v2(acc[orow % 5][1]);
            f32x4 o = {lo.x, lo.y, hi.x, hi.y};
            *(f32x4*)(op + (size_t)orow * WW) = o;
        }
    }
}

extern "C" void kernel_launch(void* const* d_in, const int* in_sizes, int n_in,
                              void* d_out, int out_size, void* d_ws, size_t ws_size,
                              hipStream_t stream) {
    const float* x  = (const float*)d_in[0];
    const float* wE = (const float*)d_in[1];
    const float* bE = (const float*)d_in[2];
    const float* wS = (const float*)d_in[3];
    const float* bS = (const float*)d_in[4];
    float* out = (float*)d_out;

    int nblocks = NIMG * (HH / TBH);   // 12 * 128 = 1536
    conv5_kernel<<<nblocks, 256, 0, stream>>>(x, wE, bE, wS, bS, out);
}

// Round 15
// 24.177 us; speedup vs baseline: 1.0617x; 1.0617x over previous
//
#include <hip/hip_runtime.h>
#include <hip/hip_bf16.h>

// Decompose: algebraically a single 5x5 conv with scalar taps
//   a_k = wS_k . wE_k  (k = i*5+j), bias = sum_k (wS_k . bE_k + bS_k)
//   out = clip( (sum_k a_k * xp[h+i, w+j] + bias) / 25, 0, 1 )
// over xp = reflect-pad(clip(x,0,1), 2). Shapes: x (4,3,1024,1024) fp32.
//
// R15: kill the 2x horizontal request amplification. Request-traffic model
// fits R6/R13/R14: time ~= [96MB*(1+4/TBH) + 48MB] / ~6.8 TB/s -- the
// kernel is request-BW bound in the cache hierarchy (HBM only sees 3.3TB/s;
// L3 absorbs halo re-reads). Previously each thread loaded 2 overlapping
// 16B chunks/row (every byte requested twice). Now: ONE aligned 16B own
// chunk/row/thread; halo via 4 ds_bpermute (lane+-1); wave-edge lanes get
// halo from an 8B edge load (2 cachelines/wave/row). Waves own contiguous
// 256-col strips. Requests: 48*1.25*1.02 + 48 ~= 109 MB -> ~16-17us.

#define HH 1024
#define WW 1024
#define NIMG 12
#define TBH 16             // output rows per block
#define ROWS (TBH + 4)     // 20 input rows touched
#define PF 6               // rolling load-buffer depth (rows)

typedef float f32x4 __attribute__((ext_vector_type(4)));
typedef float f32x2 __attribute__((ext_vector_type(2)));

__device__ __forceinline__ float readlane_f(float v, int lane) {
    return __int_as_float(__builtin_amdgcn_readlane(__float_as_int(v), lane));
}

__device__ __forceinline__ float sgpr_bcast(float v) {
    return __int_as_float(__builtin_amdgcn_readfirstlane(__float_as_int(v)));
}

__device__ __forceinline__ float bperm_f(int byteidx, float v) {
    return __int_as_float(__builtin_amdgcn_ds_bpermute(byteidx, __float_as_int(v)));
}

__device__ __forceinline__ float dot4(f32x4 a, f32x4 b) {
    return a.x * b.x + a.y * b.y + a.z * b.z + a.w * b.w;
}

__device__ __forceinline__ f32x4 clip01v4(f32x4 v) {
    f32x4 z = {0.f, 0.f, 0.f, 0.f};
    f32x4 o = {1.f, 1.f, 1.f, 1.f};
    return __builtin_elementwise_min(__builtin_elementwise_max(v, z), o);
}

__device__ __forceinline__ f32x2 clip01v2(f32x2 v) {
    f32x2 z = {0.f, 0.f};
    f32x2 o = {1.f, 1.f};
    return __builtin_elementwise_min(__builtin_elementwise_max(v, z), o);
}

__global__ __launch_bounds__(256) void conv5_kernel(const float* __restrict__ x,
                                                    const float* __restrict__ wE,
                                                    const float* __restrict__ bE,
                                                    const float* __restrict__ wS,
                                                    const float* __restrict__ bS,
                                                    float* __restrict__ out) {
    int lane = threadIdx.x & 63;

    // ---- Lane-parallel constant prep (per wave, redundant; ~300 cyc) ----
    float apass[2], cacc = 0.f;
    #pragma unroll
    for (int p = 0; p < 2; ++p) {
        int k = p * 16 + (lane >> 2);
        float a = 0.f;
        if (k < 25) {
            int base = k * 64 + (lane & 3) * 16;
            #pragma unroll
            for (int i = 0; i < 4; ++i) {
                f32x4 sv = *(const f32x4*)(wS + base + 4 * i);
                f32x4 ev = *(const f32x4*)(wE + base + 4 * i);
                f32x4 bv = *(const f32x4*)(bE + base + 4 * i);
                a += dot4(sv, ev);
                cacc += dot4(sv, bv);
            }
        }
        a += __shfl_xor(a, 1);
        a += __shfl_xor(a, 2);     // all 4 lanes of the group hold a_k
        apass[p] = a;
    }
    if (lane < 25) cacc += bS[lane];
    #pragma unroll
    for (int off = 32; off; off >>= 1) cacc += __shfl_xor(cacc, off);
    float bias = sgpr_bcast(cacc * (1.f / 25.f));
    f32x2 bias2 = {bias, bias};

    float wv[25];
    #pragma unroll
    for (int k = 0; k < 16; ++k) wv[k] = readlane_f(apass[0], 4 * k) * (1.f / 25.f);
    #pragma unroll
    for (int k = 16; k < 25; ++k) wv[k] = readlane_f(apass[1], 4 * (k - 16)) * (1.f / 25.f);

    // ---- Tile mapping: XCD-aware bijective swizzle (768 % 8 == 0) ----
    int nwg = gridDim.x;
    int cpx = nwg >> 3;
    int l = (blockIdx.x & 7) * cpx + (blockIdx.x >> 3);
    int img = l >> 6;                         // 64 row-blocks per image
    int rb = l & 63;
    int row0 = rb * TBH;

    const float* src = x + (size_t)img * (HH * WW);
    int tid = threadIdx.x;
    int cbase = tid * 4;                      // own cols [cbase..cbase+3], 16B aligned

    // Wave strip: 256 cols. Edge-halo source addresses (block-uniform per wave).
    int strip = cbase >> 8;                   // wave index within row
    int s = strip << 8;                       // strip base col
    bool img_lt = (s == 0);
    bool img_rt = (s + 256 == WW);
    // lanes<32 load the left pair {x[s-2],x[s-1]}, lanes>=32 the right pair
    // {x[s+256],x[s+257]}; clamped dummies at image edges (values unused).
    int eaddr = (lane < 32) ? (img_lt ? 0 : s - 2)
                            : (img_rt ? s + 252 : s + 256);
    bool l0 = (lane == 0);
    bool l63 = (lane == 63);
    int lm1 = ((lane - 1) & 63) << 2;         // bpermute byte indices
    int lp1 = ((lane + 1) & 63) << 2;

    // Row pointer with vertical reflection (block-uniform scalar math).
    auto rowptr = [&](int ir) -> const float* {
        int prow = row0 - 2 + ir;
        int sr = prow < 0 ? -prow : (prow >= HH ? 2 * HH - 2 - prow : prow);
        return src + (size_t)sr * WW;
    };

    // ---- Rolling structures ----
    f32x4 bufC[PF];                  // own 16B chunk per row
    f32x2 bufE[PF];                  // wave-edge halo pair per row
    f32x2 acc[5][2];                 // rotating output-row accumulators (packed)

    #pragma unroll
    for (int ir = 0; ir < PF; ++ir) {
        const float* rp = rowptr(ir);
        bufC[ir] = *(const f32x4*)(rp + cbase);
        bufE[ir] = *(const f32x2*)(rp + eaddr);
    }
    __builtin_amdgcn_sched_barrier(0);   // keep prologue loads hoisted

    float* op = out + (size_t)img * (HH * WW) + (size_t)row0 * WW + cbase;

    #pragma unroll
    for (int ir = 0; ir < ROWS; ++ir) {
        f32x4 C = bufC[ir % PF];
        f32x2 E = bufE[ir % PF];
        if (ir + PF < ROWS) {
            const float* rp = rowptr(ir + PF);
            bufC[ir % PF] = *(const f32x4*)(rp + cbase);
            bufE[ir % PF] = *(const f32x2*)(rp + eaddr);
        }

        C = clip01v4(C);
        E = clip01v2(E);

        // Halo via cross-lane: lane-1's {z,w}, lane+1's {x,y}.
        float lz = bperm_f(lm1, C.z);
        float lw = bperm_f(lm1, C.w);
        float rx = bperm_f(lp1, C.x);
        float ry = bperm_f(lp1, C.y);

        // Wave-edge + image-reflect overrides (branchless, 2 lanes affected).
        float r8[8];
        r8[0] = l0  ? (img_lt ? C.z : E.x) : lz;
        r8[1] = l0  ? (img_lt ? C.y : E.y) : lw;
        r8[2] = C.x; r8[3] = C.y; r8[4] = C.z; r8[5] = C.w;
        r8[6] = l63 ? (img_rt ? C.z : E.x) : rx;
        r8[7] = l63 ? (img_rt ? C.y : E.y) : ry;

        // Sliding pairs: pr[j] = {r8[j], r8[j+1]}, j = 0..6.
        f32x2 pr[7];
        #pragma unroll
        for (int j = 0; j < 7; ++j) { pr[j].x = r8[j]; pr[j].y = r8[j + 1]; }

        // Output row ir starts here: init its slot with the bias.
        if (ir < TBH) {
            acc[ir % 5][0] = bias2;
            acc[ir % 5][1] = bias2;
        }

        // Input row ir contributes to output rows ir-4 .. ir (packed FMA).
        #pragma unroll
        for (int dr = 0; dr < 5; ++dr) {
            int orow = ir - dr;
            if (orow < 0 || orow >= TBH) continue;
            #pragma unroll
            for (int j = 0; j < 5; ++j) {
                float wj = wv[dr * 5 + j];
                f32x2 w2 = {wj, wj};
                acc[orow % 5][0] += pr[j] * w2;       // cols 0,1
                acc[orow % 5][1] += pr[j + 2] * w2;   // cols 2,3
            }
        }

        // Output row ir-4 is final: packed clip, plain coalesced store.
        if (ir >= 4) {
            int orow = ir - 4;
            f32x2 lo = clip01v2(acc[orow % 5][0]);
            f32x2 hi = clip01v2(acc[orow % 5][1]);
            f32x4 o = {lo.x, lo.y, hi.x, hi.y};
            *(f32x4*)(op + (size_t)orow * WW) = o;
        }
    }
}

extern "C" void kernel_launch(void* const* d_in, const int* in_sizes, int n_in,
                              void* d_out, int out_size, void* d_ws, size_t ws_size,
                              hipStream_t stream) {
    const float* x  = (const float*)d_in[0];
    const float* wE = (const float*)d_in[1];
    const float* bE = (const float*)d_in[2];
    const float* wS = (const float*)d_in[3];
    const float* bS = (const float*)d_in[4];
    float* out = (float*)d_out;

    int nblocks = NIMG * (HH / TBH);   // 12 * 64 = 768
    conv5_kernel<<<nblocks, 256, 0, stream>>>(x, wE, bE, wS, bS, out);
}